// Round 4
// baseline (130.443 us; speedup 1.0000x reference)
//
#include <hip/hip_runtime.h>
#include <stdint.h>
#include <math.h>

#define B_N 512
#define M_N 65536
#define D_N 256
#define C_N 10
#define TEMP_INV 14.285714285714286f   // 1/0.07
#define LOG2E_F 1.4426950408889634f
#define K2C (LOG2E_F * TEMP_INV)       // exp(x/T) = exp2(x*K2C)

typedef __attribute__((ext_vector_type(8))) __bf16 bf16x8;
typedef __attribute__((ext_vector_type(4))) float f32x4;

__device__ __forceinline__ unsigned short f2bf(float f) {
  unsigned int u = __float_as_uint(f);
  return (unsigned short)((u + 0x7FFFu + ((u >> 16) & 1u)) >> 16);  // RNE
}
__device__ __forceinline__ float bf2f(unsigned short s) {
  return __uint_as_float(((unsigned int)s) << 16);
}

// K1: fused normalize. Blocks [0,2048): pro_memory -> bf16 pnb.
// Blocks [2048,2080): q -> f32 qn + bf16 qnb. Block 0 inits accumulators.
__global__ __launch_bounds__(256) void k_norm_full(const float* __restrict__ pm,
                                                   const float* __restrict__ q,
                                                   unsigned short* __restrict__ pnb,
                                                   float* __restrict__ qn,
                                                   unsigned short* __restrict__ qnb,
                                                   float* __restrict__ P,
                                                   int* __restrict__ cnt,
                                                   float* __restrict__ Zt,
                                                   float* __restrict__ Ss,
                                                   float* __restrict__ ns_,
                                                   float* __restrict__ out) {
  const int tid = threadIdx.x, w = tid >> 6, l = tid & 63;
  const int g = l >> 4, qs = l & 15;
  if (blockIdx.x == 0) {
    for (int i = tid; i < C_N * D_N; i += 256) P[i] = 0.f;
    if (tid < C_N) cnt[tid] = 0;
    for (int i = tid; i < B_N; i += 256) { Zt[i] = 0.f; Ss[i] = 0.f; ns_[i] = 0.f; }
    if (tid == 0) out[0] = 0.f;
  }
  if (blockIdx.x < 2048) {
    const int rbase = blockIdx.x * 32 + w * 8;
#pragma unroll
    for (int it = 0; it < 2; ++it) {
      const int r = rbase + it * 4 + g;
      const float* src = pm + (size_t)r * D_N;
      float4 v[4];
#pragma unroll
      for (int c = 0; c < 4; ++c) v[c] = *(const float4*)(src + qs * 4 + c * 64);
      float ss = 0.f;
#pragma unroll
      for (int c = 0; c < 4; ++c)
        ss += v[c].x * v[c].x + v[c].y * v[c].y + v[c].z * v[c].z + v[c].w * v[c].w;
      ss += __shfl_xor(ss, 1, 64);
      ss += __shfl_xor(ss, 2, 64);
      ss += __shfl_xor(ss, 4, 64);
      ss += __shfl_xor(ss, 8, 64);
      const float rv = 1.0f / fmaxf(sqrtf(ss), 1e-8f);
      unsigned short* dst = pnb + (size_t)r * D_N;
#pragma unroll
      for (int c = 0; c < 4; ++c) {
        ushort4 o;
        o.x = f2bf(v[c].x * rv); o.y = f2bf(v[c].y * rv);
        o.z = f2bf(v[c].z * rv); o.w = f2bf(v[c].w * rv);
        *(ushort4*)(dst + qs * 4 + c * 64) = o;
      }
    }
  } else {
    const int r = (blockIdx.x - 2048) * 16 + w * 4 + g;
    const float* src = q + (size_t)r * D_N;
    float4 v[4];
#pragma unroll
    for (int c = 0; c < 4; ++c) v[c] = *(const float4*)(src + qs * 4 + c * 64);
    float ss = 0.f;
#pragma unroll
    for (int c = 0; c < 4; ++c)
      ss += v[c].x * v[c].x + v[c].y * v[c].y + v[c].z * v[c].z + v[c].w * v[c].w;
    ss += __shfl_xor(ss, 1, 64);
    ss += __shfl_xor(ss, 2, 64);
    ss += __shfl_xor(ss, 4, 64);
    ss += __shfl_xor(ss, 8, 64);
    const float rv = 1.0f / fmaxf(sqrtf(ss), 1e-8f);
    float* dstf = qn + (size_t)r * D_N;
    unsigned short* dstb = qnb + (size_t)r * D_N;
#pragma unroll
    for (int c = 0; c < 4; ++c) {
      float4 o4;
      o4.x = v[c].x * rv; o4.y = v[c].y * rv; o4.z = v[c].z * rv; o4.w = v[c].w * rv;
      *(float4*)(dstf + qs * 4 + c * 64) = o4;
      ushort4 o;
      o.x = f2bf(o4.x); o.y = f2bf(o4.y); o.z = f2bf(o4.z); o.w = f2bf(o4.w);
      *(ushort4*)(dstb + qs * 4 + c * 64) = o;
    }
  }
}

// K2 mega-kernel:
//   blocks [0,1024): Z_mem GEMM, 64 m-rows x full 512 q. pnb tile staged ONCE
//                    (32 KB, full K), qnb tiles double-buffered, 1 barrier/step.
//   blocks [1024,1040): src branch (verified 128x128 core).
//   blocks [1040,1552): class partial sums (no LDS).
__global__ __launch_bounds__(256, 2) void k_mega(const unsigned short* __restrict__ qnb,
                                                 const unsigned short* __restrict__ pnb,
                                                 const int* __restrict__ labels,
                                                 const int* __restrict__ pl,
                                                 float* __restrict__ Zt,
                                                 float* __restrict__ Ss,
                                                 float* __restrict__ ns_,
                                                 float* __restrict__ part,
                                                 int* __restrict__ cntp) {
  __shared__ __align__(16) unsigned char smem[69632];
  const int bid = blockIdx.x;
  const int tid = threadIdx.x, w = tid >> 6, lane = tid & 63;
  const int rsel = lane & 15, hi = lane >> 4;

  if (bid < 1024) {
    // ---------------- Z_mem branch ----------------
    const int mt = bid;
    const int wr = w >> 1, wc = w & 1;
    unsigned short* Bs = (unsigned short*)smem;            // 64 x 256 (32 KB)
    unsigned short* As = (unsigned short*)(smem + 32768);  // 2 x (128 x 64) (32 KB)
    float* zall = (float*)(smem + 65536);                  // [2][512] (4 KB)
    for (int i = tid; i < 1024; i += 256) zall[i] = 0.f;
    const unsigned short* Bb = pnb + (size_t)(mt * 64) * D_N;
    // stage B tile once: 64 rows x 256 k, swizzled source (rule #21)
#pragma unroll
    for (int i = 0; i < 8; ++i) {
      const int cbase = i * 256 + w * 64;
      const int c = cbase + lane;
      const int r = c >> 5, slot = c & 31;
      __builtin_amdgcn_global_load_lds(
          (const __attribute__((address_space(1))) void*)(Bb + (size_t)r * D_N + ((slot ^ (r & 7)) * 8)),
          (__attribute__((address_space(3))) void*)(Bs + cbase * 8), 16, 0, 0);
    }
#define STAGE_A(bt_, ks_, buf_) do {                                          \
      const unsigned short* Asrc = qnb + (size_t)((bt_) * 128) * D_N + (ks_) * 64; \
      unsigned short* Adst = As + (buf_) * 8192;                              \
      _Pragma("unroll")                                                       \
      for (int i_ = 0; i_ < 4; ++i_) {                                        \
        const int cbase_ = i_ * 256 + w * 64;                                 \
        const int c_ = cbase_ + lane;                                         \
        const int r_ = c_ >> 3, slot_ = c_ & 7;                               \
        __builtin_amdgcn_global_load_lds(                                     \
            (const __attribute__((address_space(1))) void*)(Asrc + (size_t)r_ * D_N + ((slot_ ^ (r_ & 7)) * 8)), \
            (__attribute__((address_space(3))) void*)(Adst + cbase_ * 8), 16, 0, 0); \
      }                                                                       \
    } while (0)
    STAGE_A(0, 0, 0);
    __syncthreads();
    int cur = 0;
#pragma unroll
    for (int bt = 0; bt < 4; ++bt) {
      f32x4 acc[4][2];
#pragma unroll
      for (int mi = 0; mi < 4; ++mi)
#pragma unroll
        for (int ni = 0; ni < 2; ++ni)
          acc[mi][ni] = (f32x4){0.f, 0.f, 0.f, 0.f};
#pragma unroll
      for (int ks = 0; ks < 4; ++ks) {
        const int step = bt * 4 + ks;
        if (step < 15) {
          const int ns = step + 1;
          STAGE_A(ns >> 2, ns & 3, cur ^ 1);
        }
        const unsigned short* Ac = As + cur * 8192;
#pragma unroll
        for (int ksl = 0; ksl < 2; ++ksl) {
          const int sb = ksl * 4 + hi;
          bf16x8 af[4], bf[2];
#pragma unroll
          for (int mi = 0; mi < 4; ++mi) {
            const int r = wr * 64 + mi * 16 + rsel;
            af[mi] = *(const bf16x8*)((const char*)Ac + r * 128 + ((sb ^ (r & 7)) * 16));
          }
          const int slot = ks * 8 + ksl * 4 + hi;
#pragma unroll
          for (int ni = 0; ni < 2; ++ni) {
            const int rB = wc * 32 + ni * 16 + rsel;
            bf[ni] = *(const bf16x8*)((const char*)Bs + rB * 512 + ((slot ^ (rB & 7)) * 16));
          }
#pragma unroll
          for (int mi = 0; mi < 4; ++mi)
#pragma unroll
            for (int ni = 0; ni < 2; ++ni)
              acc[mi][ni] = __builtin_amdgcn_mfma_f32_16x16x32_bf16(af[mi], bf[ni], acc[mi][ni], 0, 0, 0);
        }
        __syncthreads();
        cur ^= 1;
      }
      // epilogue for this q-tile: sum exp over the block's 64 m-cols
#pragma unroll
      for (int mi = 0; mi < 4; ++mi) {
        float sv[4] = {0.f, 0.f, 0.f, 0.f};
#pragma unroll
        for (int ni = 0; ni < 2; ++ni)
#pragma unroll
          for (int rg = 0; rg < 4; ++rg)
            sv[rg] += __builtin_amdgcn_exp2f(acc[mi][ni][rg] * K2C);
#pragma unroll
        for (int rg = 0; rg < 4; ++rg) {
          float v = sv[rg];
          v += __shfl_xor(v, 1, 64);
          v += __shfl_xor(v, 2, 64);
          v += __shfl_xor(v, 4, 64);
          v += __shfl_xor(v, 8, 64);
          if (rsel == 0) {
            const int rl = bt * 128 + wr * 64 + mi * 16 + hi * 4 + rg;
            zall[wc * 512 + rl] += v;   // wave-private address: no atomic needed
          }
        }
      }
    }
    __syncthreads();
    for (int i = tid; i < 512; i += 256)
      atomicAdd(&Zt[i], zall[i] + zall[512 + i]);
#undef STAGE_A
  } else if (bid < 1040) {
    // ---------------- src branch (verified 128x128 core) ----------------
    unsigned short* As = (unsigned short*)smem;            // 128x64
    unsigned short* Bs = (unsigned short*)(smem + 16384);  // 128x64
    int* labR = (int*)(smem + 32768);
    int* labJ = (int*)(smem + 33280);
    float* zr = (float*)(smem + 33792);
    float* sr = (float*)(smem + 34304);
    float* nr = (float*)(smem + 34816);
    const int sb_id = bid - 1024;
    const int bt = sb_id >> 2, jt = sb_id & 3;
    const unsigned short* Ab = qnb + (size_t)(bt * 128) * D_N;
    const unsigned short* Bb = qnb + (size_t)(jt * 128) * D_N;
    if (tid < 128) {
      labR[tid] = labels[bt * 128 + tid];
      labJ[tid] = labels[jt * 128 + tid];
      zr[tid] = 0.f; sr[tid] = 0.f; nr[tid] = 0.f;
    }
    f32x4 acc[4][4];
#pragma unroll
    for (int mi = 0; mi < 4; ++mi)
#pragma unroll
      for (int ni = 0; ni < 4; ++ni)
        acc[mi][ni] = (f32x4){0.f, 0.f, 0.f, 0.f};
    const int wr = w >> 1, wc = w & 1;
    for (int ks = 0; ks < 4; ++ks) {
      const int kk = ks * 64;
#pragma unroll
      for (int i = 0; i < 4; ++i) {
        const int cbase = i * 256 + w * 64;
        const int c = cbase + lane;
        const int r = c >> 3;
        const int ss2 = (c & 7) ^ (r & 7);
        __builtin_amdgcn_global_load_lds(
            (const __attribute__((address_space(1))) void*)(Ab + (size_t)r * D_N + kk + ss2 * 8),
            (__attribute__((address_space(3))) void*)(As + cbase * 8), 16, 0, 0);
        __builtin_amdgcn_global_load_lds(
            (const __attribute__((address_space(1))) void*)(Bb + (size_t)r * D_N + kk + ss2 * 8),
            (__attribute__((address_space(3))) void*)(Bs + cbase * 8), 16, 0, 0);
      }
      __syncthreads();
#pragma unroll
      for (int ksl = 0; ksl < 2; ++ksl) {
        const int sb = ksl * 4 + hi;
        bf16x8 af[4], bfr[4];
#pragma unroll
        for (int mi = 0; mi < 4; ++mi) {
          const int r = wr * 64 + mi * 16 + rsel;
          af[mi] = *(const bf16x8*)((const char*)As + r * 128 + ((sb ^ (r & 7)) * 16));
        }
#pragma unroll
        for (int ni = 0; ni < 4; ++ni) {
          const int r = wc * 64 + ni * 16 + rsel;
          bfr[ni] = *(const bf16x8*)((const char*)Bs + r * 128 + ((sb ^ (r & 7)) * 16));
        }
#pragma unroll
        for (int mi = 0; mi < 4; ++mi)
#pragma unroll
          for (int ni = 0; ni < 4; ++ni)
            acc[mi][ni] = __builtin_amdgcn_mfma_f32_16x16x32_bf16(af[mi], bfr[ni], acc[mi][ni], 0, 0, 0);
      }
      __syncthreads();
    }
#pragma unroll
    for (int mi = 0; mi < 4; ++mi) {
      float zs[4] = {0.f, 0.f, 0.f, 0.f};
      float sv[4] = {0.f, 0.f, 0.f, 0.f};
      float nv[4] = {0.f, 0.f, 0.f, 0.f};
#pragma unroll
      for (int ni = 0; ni < 4; ++ni) {
        const int j_loc = wc * 64 + ni * 16 + rsel;
        const int jg = jt * 128 + j_loc;
        const int lj = labJ[j_loc];
#pragma unroll
        for (int rg_ = 0; rg_ < 4; ++rg_) {
          const int r_loc = wr * 64 + mi * 16 + hi * 4 + rg_;
          const int rg = bt * 128 + r_loc;
          const float lg = acc[mi][ni][rg_] * TEMP_INV - TEMP_INV;
          if (rg != jg) {
            zs[rg_] += __builtin_amdgcn_exp2f(lg * LOG2E_F);
            if (labR[r_loc] == lj) { sv[rg_] += lg; nv[rg_] += 1.f; }
          }
        }
      }
#pragma unroll
      for (int rg_ = 0; rg_ < 4; ++rg_) {
        float z = zs[rg_], s = sv[rg_], n = nv[rg_];
        z += __shfl_xor(z, 1, 64); z += __shfl_xor(z, 2, 64);
        z += __shfl_xor(z, 4, 64); z += __shfl_xor(z, 8, 64);
        s += __shfl_xor(s, 1, 64); s += __shfl_xor(s, 2, 64);
        s += __shfl_xor(s, 4, 64); s += __shfl_xor(s, 8, 64);
        n += __shfl_xor(n, 1, 64); n += __shfl_xor(n, 2, 64);
        n += __shfl_xor(n, 4, 64); n += __shfl_xor(n, 8, 64);
        if (rsel == 0) {
          const int r_loc = wr * 64 + mi * 16 + hi * 4 + rg_;
          atomicAdd(&zr[r_loc], z);
          atomicAdd(&sr[r_loc], s);
          atomicAdd(&nr[r_loc], n);
        }
      }
    }
    __syncthreads();
    if (tid < 128) {
      atomicAdd(&Zt[bt * 128 + tid], zr[tid]);
      atomicAdd(&Ss[bt * 128 + tid], sr[tid]);
      atomicAdd(&ns_[bt * 128 + tid], nr[tid]);
    }
  } else {
    // ---------------- class partial-sum branch ----------------
    const int cb = bid - 1040;
    const int rbase = cb * 128;
    float a0 = 0.f, a1 = 0.f, a2 = 0.f, a3 = 0.f, a4 = 0.f;
    float a5 = 0.f, a6 = 0.f, a7 = 0.f, a8 = 0.f, a9 = 0.f;
    int c0 = 0, c1 = 0, c2 = 0, c3 = 0, c4 = 0;
    int c5 = 0, c6 = 0, c7 = 0, c8 = 0, c9 = 0;
    for (int it = 0; it < 128; it += 8) {
      float v[8];
      int cl[8];
#pragma unroll
      for (int j = 0; j < 8; ++j) {
        const int r = rbase + it + j;
        cl[j] = pl[r];
        v[j] = bf2f(pnb[(size_t)r * D_N + tid]);
      }
#pragma unroll
      for (int j = 0; j < 8; ++j) {
        const float vv = v[j];
        switch (cl[j]) {
          case 0: a0 += vv; c0++; break;
          case 1: a1 += vv; c1++; break;
          case 2: a2 += vv; c2++; break;
          case 3: a3 += vv; c3++; break;
          case 4: a4 += vv; c4++; break;
          case 5: a5 += vv; c5++; break;
          case 6: a6 += vv; c6++; break;
          case 7: a7 += vv; c7++; break;
          case 8: a8 += vv; c8++; break;
          default: a9 += vv; c9++; break;
        }
      }
    }
    float* dst = part + (size_t)cb * (C_N * D_N) + tid;
    dst[0] = a0; dst[256] = a1; dst[512] = a2; dst[768] = a3; dst[1024] = a4;
    dst[1280] = a5; dst[1536] = a6; dst[1792] = a7; dst[2048] = a8; dst[2304] = a9;
    if (tid == 0) {
      int* cd = cntp + cb * C_N;
      cd[0] = c0; cd[1] = c1; cd[2] = c2; cd[3] = c3; cd[4] = c4;
      cd[5] = c5; cd[6] = c6; cd[7] = c7; cd[8] = c8; cd[9] = c9;
    }
  }
}

// K3: reduce class partials. 40 blocks = 10 classes x 4 chunks of 128.
__global__ __launch_bounds__(256) void k_class_reduce(const float* __restrict__ part,
                                                      const int* __restrict__ cntp,
                                                      float* __restrict__ P,
                                                      int* __restrict__ cnt) {
  __shared__ int xs[4];
  const int c = blockIdx.x >> 2, q = blockIdx.x & 3;
  const int tid = threadIdx.x, w = tid >> 6, lane = tid & 63;
  float s = 0.f;
#pragma unroll 8
  for (int i = 0; i < 128; ++i)
    s += part[(size_t)(q * 128 + i) * (C_N * D_N) + c * 256 + tid];
  atomicAdd(&P[c * 256 + tid], s);
  int x = (tid < 128) ? cntp[(q * 128 + tid) * C_N + c] : 0;
  x += __shfl_xor(x, 32, 64);
  x += __shfl_xor(x, 16, 64);
  x += __shfl_xor(x, 8, 64);
  x += __shfl_xor(x, 4, 64);
  x += __shfl_xor(x, 2, 64);
  x += __shfl_xor(x, 1, 64);
  if (lane == 0) xs[w] = x;
  __syncthreads();
  if (tid == 0) atomicAdd(&cnt[c], xs[0] + xs[1]);
}

// K4: loss. 128 blocks, 1 row per wave.
__global__ __launch_bounds__(256) void k_final(const float* __restrict__ qn,
                                               const int* __restrict__ labels,
                                               const float* __restrict__ P,
                                               const int* __restrict__ cnt,
                                               const float* __restrict__ Zt,
                                               const float* __restrict__ Ss,
                                               const float* __restrict__ ns_,
                                               float* __restrict__ out) {
  __shared__ float part[4];
  const int tid = threadIdx.x, w = tid >> 6, lane = tid & 63;
  const int b = blockIdx.x * 4 + w;
  const int cls = labels[b];
  const float4 v = *(const float4*)(qn + (size_t)b * D_N + lane * 4);
  const float4 p = *(const float4*)(P + (size_t)cls * D_N + lane * 4);
  float d = v.x * p.x + v.y * p.y + v.z * p.z + v.w * p.w;
  d += __shfl_xor(d, 32, 64);
  d += __shfl_xor(d, 16, 64);
  d += __shfl_xor(d, 8, 64);
  d += __shfl_xor(d, 4, 64);
  d += __shfl_xor(d, 2, 64);
  d += __shfl_xor(d, 1, 64);
  if (lane == 0) {
    const float smem_ = d * TEMP_INV;
    const float ntot = ns_[b] + (float)cnt[cls];
    part[w] = (Ss[b] + smem_) / ntot - logf(Zt[b]);
  }
  __syncthreads();
  if (tid == 0)
    atomicAdd(out, -(part[0] + part[1] + part[2] + part[3]) * (1.0f / (float)B_N));
}

extern "C" void kernel_launch(void* const* d_in, const int* in_sizes, int n_in,
                              void* d_out, int out_size, void* d_ws, size_t ws_size,
                              hipStream_t stream) {
  const float* q = (const float*)d_in[0];
  const int* labels = (const int*)d_in[1];
  const float* pm = (const float*)d_in[2];
  const int* pl = (const int*)d_in[3];
  float* out = (float*)d_out;

  char* wsb = (char*)d_ws;
  unsigned short* pnb = (unsigned short*)wsb;              // 33,554,432 B
  float* qn = (float*)(wsb + 33554432);                    // 524,288 B
  unsigned short* qnb = (unsigned short*)(wsb + 34078720); // 262,144 B
  float* P = (float*)(wsb + 34340864);                     // 10,240 B
  int* cnt = (int*)(wsb + 34351104);                       // 64 B
  float* Zt = (float*)(wsb + 34351168);                    // 2,048 B
  float* Ss = (float*)(wsb + 34353216);                    // 2,048 B
  float* ns_ = (float*)(wsb + 34355264);                   // 2,048 B
  float* part = (float*)(wsb + 34357312);                  // 512*2560*4 = 5,242,880 B
  int* cntp = (int*)(wsb + 39600192);                      // 512*10*4 = 20,480 B

  k_norm_full<<<2080, 256, 0, stream>>>(pm, q, pnb, qn, qnb, P, cnt, Zt, Ss, ns_, out);
  k_mega<<<1552, 256, 0, stream>>>(qnb, pnb, labels, pl, Zt, Ss, ns_, part, cntp);
  k_class_reduce<<<40, 256, 0, stream>>>(part, cntp, P, cnt);
  k_final<<<128, 256, 0, stream>>>(qn, labels, P, cnt, Zt, Ss, ns_, out);
}

// Round 5
// 94.879 us; speedup vs baseline: 1.3748x; 1.3748x over previous
//
#include <hip/hip_runtime.h>
#include <stdint.h>
#include <math.h>

#define B_N 512
#define M_N 65536
#define D_N 256
#define C_N 10
#define TEMP_INV 14.285714285714286f   // 1/0.07
#define LOG2E_F 1.4426950408889634f
#define K2C (LOG2E_F * TEMP_INV)       // exp(x/T) = exp2(x*K2C)

typedef __attribute__((ext_vector_type(8))) __bf16 bf16x8;
typedef __attribute__((ext_vector_type(4))) float f32x4;

__device__ __forceinline__ unsigned short f2bf(float f) {
  unsigned int u = __float_as_uint(f);
  return (unsigned short)((u + 0x7FFFu + ((u >> 16) & 1u)) >> 16);  // RNE
}
__device__ __forceinline__ float bf2f(unsigned short s) {
  return __uint_as_float(((unsigned int)s) << 16);
}

// K1: fused normalize. Blocks [0,2048): pro_memory -> bf16 pnb (row-major).
// Blocks [2048,2080): q -> f32 qn + bf16 qnb (row-major, for k_src) + qnbF
// (k-chunk-major fragment layout [32][512][8] for the GEMM's direct A-loads).
// Block 0 inits accumulators.
__global__ __launch_bounds__(256) void k_norm_full(const float* __restrict__ pm,
                                                   const float* __restrict__ q,
                                                   unsigned short* __restrict__ pnb,
                                                   float* __restrict__ qn,
                                                   unsigned short* __restrict__ qnb,
                                                   unsigned short* __restrict__ qnbF,
                                                   float* __restrict__ P,
                                                   int* __restrict__ cnt,
                                                   float* __restrict__ Zt,
                                                   float* __restrict__ Ss,
                                                   float* __restrict__ ns_,
                                                   float* __restrict__ out) {
  const int tid = threadIdx.x, w = tid >> 6, l = tid & 63;
  const int g = l >> 4, qs = l & 15;
  if (blockIdx.x == 0) {
    for (int i = tid; i < C_N * D_N; i += 256) P[i] = 0.f;
    if (tid < C_N) cnt[tid] = 0;
    for (int i = tid; i < B_N; i += 256) { Zt[i] = 0.f; Ss[i] = 0.f; ns_[i] = 0.f; }
    if (tid == 0) out[0] = 0.f;
  }
  if (blockIdx.x < 2048) {
    const int rbase = blockIdx.x * 32 + w * 8;
#pragma unroll
    for (int it = 0; it < 2; ++it) {
      const int r = rbase + it * 4 + g;
      const float* src = pm + (size_t)r * D_N;
      float4 v[4];
#pragma unroll
      for (int c = 0; c < 4; ++c) v[c] = *(const float4*)(src + qs * 4 + c * 64);
      float ss = 0.f;
#pragma unroll
      for (int c = 0; c < 4; ++c)
        ss += v[c].x * v[c].x + v[c].y * v[c].y + v[c].z * v[c].z + v[c].w * v[c].w;
      ss += __shfl_xor(ss, 1, 64);
      ss += __shfl_xor(ss, 2, 64);
      ss += __shfl_xor(ss, 4, 64);
      ss += __shfl_xor(ss, 8, 64);
      const float rv = 1.0f / fmaxf(sqrtf(ss), 1e-8f);
      unsigned short* dst = pnb + (size_t)r * D_N;
#pragma unroll
      for (int c = 0; c < 4; ++c) {
        ushort4 o;
        o.x = f2bf(v[c].x * rv); o.y = f2bf(v[c].y * rv);
        o.z = f2bf(v[c].z * rv); o.w = f2bf(v[c].w * rv);
        *(ushort4*)(dst + qs * 4 + c * 64) = o;
      }
    }
  } else {
    const int r = (blockIdx.x - 2048) * 16 + w * 4 + g;
    const float* src = q + (size_t)r * D_N;
    float4 v[4];
#pragma unroll
    for (int c = 0; c < 4; ++c) v[c] = *(const float4*)(src + qs * 4 + c * 64);
    float ss = 0.f;
#pragma unroll
    for (int c = 0; c < 4; ++c)
      ss += v[c].x * v[c].x + v[c].y * v[c].y + v[c].z * v[c].z + v[c].w * v[c].w;
    ss += __shfl_xor(ss, 1, 64);
    ss += __shfl_xor(ss, 2, 64);
    ss += __shfl_xor(ss, 4, 64);
    ss += __shfl_xor(ss, 8, 64);
    const float rv = 1.0f / fmaxf(sqrtf(ss), 1e-8f);
    float* dstf = qn + (size_t)r * D_N;
    unsigned short* dstb = qnb + (size_t)r * D_N;
#pragma unroll
    for (int c = 0; c < 4; ++c) {
      float4 o4;
      o4.x = v[c].x * rv; o4.y = v[c].y * rv; o4.z = v[c].z * rv; o4.w = v[c].w * rv;
      *(float4*)(dstf + qs * 4 + c * 64) = o4;
      ushort4 o;
      o.x = f2bf(o4.x); o.y = f2bf(o4.y); o.z = f2bf(o4.z); o.w = f2bf(o4.w);
      *(ushort4*)(dstb + qs * 4 + c * 64) = o;
      // fragment layout: element e = qs*4 + c*64 (+0..3); kc = e>>3
      const int kc = (qs >> 1) + c * 8;
      *(ushort4*)(qnbF + (((size_t)kc * 512 + r) << 3) + (qs & 1) * 4) = o;
    }
  }
}

// K2 mega-kernel:
//   blocks [0,1024): Z_mem GEMM over 64 m-rows x all 512 q. B staged once in
//     LDS (swizzled, ONE barrier); A-fragments loaded directly from L2-hot
//     qnbF (no LDS, no per-step barrier). 4 waves x 32 q-rows, acc[2][4].
//     Z partials -> plain coalesced stores to Zpart[bid][512] (NO atomics).
//   blocks [1024,1040): src branch (verified 128x128 core).
//   blocks [1040,1552): class partial sums.
__global__ __launch_bounds__(256, 4) void k_mega(const unsigned short* __restrict__ qnb,
                                                 const unsigned short* __restrict__ qnbF,
                                                 const unsigned short* __restrict__ pnb,
                                                 const int* __restrict__ labels,
                                                 const int* __restrict__ pl,
                                                 float* __restrict__ Zt,
                                                 float* __restrict__ Ss,
                                                 float* __restrict__ ns_,
                                                 float* __restrict__ Zpart,
                                                 float* __restrict__ part,
                                                 int* __restrict__ cntp) {
  __shared__ __align__(16) unsigned char smem[36864];
  const int bid = blockIdx.x;
  const int tid = threadIdx.x, w = tid >> 6, lane = tid & 63;
  const int rsel = lane & 15, hi = lane >> 4;

  if (bid < 1024) {
    // ---------------- Z_mem branch ----------------
    unsigned short* Bs = (unsigned short*)smem;            // 64 x 256 (32 KB)
    float* zall = (float*)(smem + 32768);                  // [512] (2 KB)
    const unsigned short* Bb = pnb + (size_t)(bid * 64) * D_N;
    // stage B tile once: 64 rows x 256 k, inverse-swizzled source (rule #21)
#pragma unroll
    for (int i = 0; i < 8; ++i) {
      const int cbase = i * 256 + w * 64;
      const int c = cbase + lane;
      const int r = c >> 5, slot = c & 31;
      __builtin_amdgcn_global_load_lds(
          (const __attribute__((address_space(1))) void*)(Bb + (size_t)r * D_N + ((slot ^ (r & 7)) * 8)),
          (__attribute__((address_space(3))) void*)(Bs + cbase * 8), 16, 0, 0);
    }
    __syncthreads();   // the ONLY barrier before the flush

#pragma unroll
    for (int bt = 0; bt < 4; ++bt) {
      f32x4 acc[2][4];
#pragma unroll
      for (int mi = 0; mi < 2; ++mi)
#pragma unroll
        for (int ni = 0; ni < 4; ++ni)
          acc[mi][ni] = (f32x4){0.f, 0.f, 0.f, 0.f};
#pragma unroll
      for (int ks = 0; ks < 4; ++ks) {
#pragma unroll
        for (int ksl = 0; ksl < 2; ++ksl) {
          const int kc = ks * 8 + ksl * 4 + hi;   // k-chunk (16B) index
          bf16x8 af[2], bfr[4];
#pragma unroll
          for (int mi = 0; mi < 2; ++mi) {
            const int r = bt * 128 + w * 32 + mi * 16 + rsel;
            af[mi] = *(const bf16x8*)(qnbF + (((size_t)kc * 512 + r) << 3));
          }
#pragma unroll
          for (int ni = 0; ni < 4; ++ni) {
            const int rB = ni * 16 + rsel;
            bfr[ni] = *(const bf16x8*)((const char*)Bs + rB * 512 + ((kc ^ (rB & 7)) * 16));
          }
#pragma unroll
          for (int mi = 0; mi < 2; ++mi)
#pragma unroll
            for (int ni = 0; ni < 4; ++ni)
              acc[mi][ni] = __builtin_amdgcn_mfma_f32_16x16x32_bf16(af[mi], bfr[ni], acc[mi][ni], 0, 0, 0);
        }
      }
      // epilogue for this q-tile: sum exp over this block's 64 m-cols
#pragma unroll
      for (int mi = 0; mi < 2; ++mi) {
        float sv[4] = {0.f, 0.f, 0.f, 0.f};
#pragma unroll
        for (int ni = 0; ni < 4; ++ni)
#pragma unroll
          for (int rg = 0; rg < 4; ++rg)
            sv[rg] += __builtin_amdgcn_exp2f(acc[mi][ni][rg] * K2C);
#pragma unroll
        for (int rg = 0; rg < 4; ++rg) {
          float v = sv[rg];
          v += __shfl_xor(v, 1, 64);
          v += __shfl_xor(v, 2, 64);
          v += __shfl_xor(v, 4, 64);
          v += __shfl_xor(v, 8, 64);
          if (rsel == 0)
            zall[bt * 128 + w * 32 + mi * 16 + hi * 4 + rg] = v;  // owner-unique
        }
      }
    }
    __syncthreads();
    float* zp = Zpart + (size_t)bid * 512;
    for (int i = tid; i < 512; i += 256) zp[i] = zall[i];  // plain coalesced
  } else if (bid < 1040) {
    // ---------------- src branch (verified 128x128 core) ----------------
    unsigned short* As = (unsigned short*)smem;            // 128x64
    unsigned short* Bs = (unsigned short*)(smem + 16384);  // 128x64
    int* labR = (int*)(smem + 32768);
    int* labJ = (int*)(smem + 33280);
    float* zr = (float*)(smem + 33792);
    float* sr = (float*)(smem + 34304);
    float* nr = (float*)(smem + 34816);
    const int sb_id = bid - 1024;
    const int bt = sb_id >> 2, jt = sb_id & 3;
    const unsigned short* Ab = qnb + (size_t)(bt * 128) * D_N;
    const unsigned short* Bb = qnb + (size_t)(jt * 128) * D_N;
    if (tid < 128) {
      labR[tid] = labels[bt * 128 + tid];
      labJ[tid] = labels[jt * 128 + tid];
      zr[tid] = 0.f; sr[tid] = 0.f; nr[tid] = 0.f;
    }
    f32x4 acc[4][4];
#pragma unroll
    for (int mi = 0; mi < 4; ++mi)
#pragma unroll
      for (int ni = 0; ni < 4; ++ni)
        acc[mi][ni] = (f32x4){0.f, 0.f, 0.f, 0.f};
    const int wr = w >> 1, wc = w & 1;
    for (int ks = 0; ks < 4; ++ks) {
      const int kk = ks * 64;
#pragma unroll
      for (int i = 0; i < 4; ++i) {
        const int cbase = i * 256 + w * 64;
        const int c = cbase + lane;
        const int r = c >> 3;
        const int ss2 = (c & 7) ^ (r & 7);
        __builtin_amdgcn_global_load_lds(
            (const __attribute__((address_space(1))) void*)(Ab + (size_t)r * D_N + kk + ss2 * 8),
            (__attribute__((address_space(3))) void*)(As + cbase * 8), 16, 0, 0);
        __builtin_amdgcn_global_load_lds(
            (const __attribute__((address_space(1))) void*)(Bb + (size_t)r * D_N + kk + ss2 * 8),
            (__attribute__((address_space(3))) void*)(Bs + cbase * 8), 16, 0, 0);
      }
      __syncthreads();
#pragma unroll
      for (int ksl = 0; ksl < 2; ++ksl) {
        const int sb = ksl * 4 + hi;
        bf16x8 af[4], bfr[4];
#pragma unroll
        for (int mi = 0; mi < 4; ++mi) {
          const int r = wr * 64 + mi * 16 + rsel;
          af[mi] = *(const bf16x8*)((const char*)As + r * 128 + ((sb ^ (r & 7)) * 16));
        }
#pragma unroll
        for (int ni = 0; ni < 4; ++ni) {
          const int r = wc * 64 + ni * 16 + rsel;
          bfr[ni] = *(const bf16x8*)((const char*)Bs + r * 128 + ((sb ^ (r & 7)) * 16));
        }
#pragma unroll
        for (int mi = 0; mi < 4; ++mi)
#pragma unroll
          for (int ni = 0; ni < 4; ++ni)
            acc[mi][ni] = __builtin_amdgcn_mfma_f32_16x16x32_bf16(af[mi], bfr[ni], acc[mi][ni], 0, 0, 0);
      }
      __syncthreads();
    }
#pragma unroll
    for (int mi = 0; mi < 4; ++mi) {
      float zs[4] = {0.f, 0.f, 0.f, 0.f};
      float sv[4] = {0.f, 0.f, 0.f, 0.f};
      float nv[4] = {0.f, 0.f, 0.f, 0.f};
#pragma unroll
      for (int ni = 0; ni < 4; ++ni) {
        const int j_loc = wc * 64 + ni * 16 + rsel;
        const int jg = jt * 128 + j_loc;
        const int lj = labJ[j_loc];
#pragma unroll
        for (int rg_ = 0; rg_ < 4; ++rg_) {
          const int r_loc = wr * 64 + mi * 16 + hi * 4 + rg_;
          const int rg = bt * 128 + r_loc;
          const float lg = acc[mi][ni][rg_] * TEMP_INV - TEMP_INV;
          if (rg != jg) {
            zs[rg_] += __builtin_amdgcn_exp2f(lg * LOG2E_F);
            if (labR[r_loc] == lj) { sv[rg_] += lg; nv[rg_] += 1.f; }
          }
        }
      }
#pragma unroll
      for (int rg_ = 0; rg_ < 4; ++rg_) {
        float z = zs[rg_], s = sv[rg_], n = nv[rg_];
        z += __shfl_xor(z, 1, 64); z += __shfl_xor(z, 2, 64);
        z += __shfl_xor(z, 4, 64); z += __shfl_xor(z, 8, 64);
        s += __shfl_xor(s, 1, 64); s += __shfl_xor(s, 2, 64);
        s += __shfl_xor(s, 4, 64); s += __shfl_xor(s, 8, 64);
        n += __shfl_xor(n, 1, 64); n += __shfl_xor(n, 2, 64);
        n += __shfl_xor(n, 4, 64); n += __shfl_xor(n, 8, 64);
        if (rsel == 0) {
          const int r_loc = wr * 64 + mi * 16 + hi * 4 + rg_;
          atomicAdd(&zr[r_loc], z);
          atomicAdd(&sr[r_loc], s);
          atomicAdd(&nr[r_loc], n);
        }
      }
    }
    __syncthreads();
    if (tid < 128) {
      atomicAdd(&Zt[bt * 128 + tid], zr[tid]);
      atomicAdd(&Ss[bt * 128 + tid], sr[tid]);
      atomicAdd(&ns_[bt * 128 + tid], nr[tid]);
    }
  } else {
    // ---------------- class partial-sum branch ----------------
    const int cb = bid - 1040;
    const int rbase = cb * 128;
    float a0 = 0.f, a1 = 0.f, a2 = 0.f, a3 = 0.f, a4 = 0.f;
    float a5 = 0.f, a6 = 0.f, a7 = 0.f, a8 = 0.f, a9 = 0.f;
    int c0 = 0, c1 = 0, c2 = 0, c3 = 0, c4 = 0;
    int c5 = 0, c6 = 0, c7 = 0, c8 = 0, c9 = 0;
    for (int it = 0; it < 128; it += 8) {
      float v[8];
      int cl[8];
#pragma unroll
      for (int j = 0; j < 8; ++j) {
        const int r = rbase + it + j;
        cl[j] = pl[r];
        v[j] = bf2f(pnb[(size_t)r * D_N + tid]);
      }
#pragma unroll
      for (int j = 0; j < 8; ++j) {
        const float vv = v[j];
        switch (cl[j]) {
          case 0: a0 += vv; c0++; break;
          case 1: a1 += vv; c1++; break;
          case 2: a2 += vv; c2++; break;
          case 3: a3 += vv; c3++; break;
          case 4: a4 += vv; c4++; break;
          case 5: a5 += vv; c5++; break;
          case 6: a6 += vv; c6++; break;
          case 7: a7 += vv; c7++; break;
          case 8: a8 += vv; c8++; break;
          default: a9 += vv; c9++; break;
        }
      }
    }
    float* dst = part + (size_t)cb * (C_N * D_N) + tid;
    dst[0] = a0; dst[256] = a1; dst[512] = a2; dst[768] = a3; dst[1024] = a4;
    dst[1280] = a5; dst[1536] = a6; dst[1792] = a7; dst[2048] = a8; dst[2304] = a9;
    if (tid == 0) {
      int* cd = cntp + cb * C_N;
      cd[0] = c0; cd[1] = c1; cd[2] = c2; cd[3] = c3; cd[4] = c4;
      cd[5] = c5; cd[6] = c6; cd[7] = c7; cd[8] = c8; cd[9] = c9;
    }
  }
}

// K3: fused reductions. Blocks [0,40): class partials -> P/cnt.
// Blocks [40,48): Zpart columns -> Zt (+=, after src atomics are in).
__global__ __launch_bounds__(256) void k_reduce2(const float* __restrict__ part,
                                                 const int* __restrict__ cntp,
                                                 const float* __restrict__ Zpart,
                                                 float* __restrict__ P,
                                                 int* __restrict__ cnt,
                                                 float* __restrict__ Zt) {
  const int tid = threadIdx.x, w = tid >> 6, lane = tid & 63;
  if (blockIdx.x < 40) {
    __shared__ int xs[4];
    const int c = blockIdx.x >> 2, q = blockIdx.x & 3;
    float s = 0.f;
#pragma unroll 8
    for (int i = 0; i < 128; ++i)
      s += part[(size_t)(q * 128 + i) * (C_N * D_N) + c * 256 + tid];
    atomicAdd(&P[c * 256 + tid], s);
    int x = (tid < 128) ? cntp[(q * 128 + tid) * C_N + c] : 0;
    x += __shfl_xor(x, 32, 64);
    x += __shfl_xor(x, 16, 64);
    x += __shfl_xor(x, 8, 64);
    x += __shfl_xor(x, 4, 64);
    x += __shfl_xor(x, 2, 64);
    x += __shfl_xor(x, 1, 64);
    if (lane == 0) xs[w] = x;
    __syncthreads();
    if (tid == 0) atomicAdd(&cnt[c], xs[0] + xs[1]);
  } else {
    __shared__ float zl[4][64];
    const int zb = blockIdx.x - 40;
    const int b = zb * 64 + (tid & 63);
    const int s = tid >> 6;
    float acc = 0.f;
#pragma unroll 8
    for (int k = 0; k < 256; ++k)
      acc += Zpart[(size_t)(s * 256 + k) * 512 + b];
    zl[s][tid & 63] = acc;
    __syncthreads();
    if (tid < 64)
      Zt[zb * 64 + tid] += zl[0][tid] + zl[1][tid] + zl[2][tid] + zl[3][tid];
  }
}

// K4: loss. 128 blocks, 1 row per wave.
__global__ __launch_bounds__(256) void k_final(const float* __restrict__ qn,
                                               const int* __restrict__ labels,
                                               const float* __restrict__ P,
                                               const int* __restrict__ cnt,
                                               const float* __restrict__ Zt,
                                               const float* __restrict__ Ss,
                                               const float* __restrict__ ns_,
                                               float* __restrict__ out) {
  __shared__ float partl[4];
  const int tid = threadIdx.x, w = tid >> 6, lane = tid & 63;
  const int b = blockIdx.x * 4 + w;
  const int cls = labels[b];
  const float4 v = *(const float4*)(qn + (size_t)b * D_N + lane * 4);
  const float4 p = *(const float4*)(P + (size_t)cls * D_N + lane * 4);
  float d = v.x * p.x + v.y * p.y + v.z * p.z + v.w * p.w;
  d += __shfl_xor(d, 32, 64);
  d += __shfl_xor(d, 16, 64);
  d += __shfl_xor(d, 8, 64);
  d += __shfl_xor(d, 4, 64);
  d += __shfl_xor(d, 2, 64);
  d += __shfl_xor(d, 1, 64);
  if (lane == 0) {
    const float smem_ = d * TEMP_INV;
    const float ntot = ns_[b] + (float)cnt[cls];
    partl[w] = (Ss[b] + smem_) / ntot - logf(Zt[b]);
  }
  __syncthreads();
  if (tid == 0)
    atomicAdd(out, -(partl[0] + partl[1] + partl[2] + partl[3]) * (1.0f / (float)B_N));
}

extern "C" void kernel_launch(void* const* d_in, const int* in_sizes, int n_in,
                              void* d_out, int out_size, void* d_ws, size_t ws_size,
                              hipStream_t stream) {
  const float* q = (const float*)d_in[0];
  const int* labels = (const int*)d_in[1];
  const float* pm = (const float*)d_in[2];
  const int* pl = (const int*)d_in[3];
  float* out = (float*)d_out;

  char* wsb = (char*)d_ws;
  unsigned short* pnb = (unsigned short*)wsb;              // 33,554,432 B
  float* qn = (float*)(wsb + 33554432);                    // 524,288 B
  unsigned short* qnb = (unsigned short*)(wsb + 34078720); // 262,144 B
  float* P = (float*)(wsb + 34340864);                     // 10,240 B
  int* cnt = (int*)(wsb + 34351104);                       // 64 B
  float* Zt = (float*)(wsb + 34351168);                    // 2,048 B
  float* Ss = (float*)(wsb + 34353216);                    // 2,048 B
  float* ns_ = (float*)(wsb + 34355264);                   // 2,048 B
  float* part = (float*)(wsb + 34357312);                  // 512*2560*4 = 5,242,880 B
  int* cntp = (int*)(wsb + 39600192);                      // 512*10*4 = 20,480 B
  float* Zpart = (float*)(wsb + 39620672);                 // 1024*512*4 = 2,097,152 B
  unsigned short* qnbF = (unsigned short*)(wsb + 41717824);// 32*512*8*2 = 262,144 B

  k_norm_full<<<2080, 256, 0, stream>>>(pm, q, pnb, qn, qnb, qnbF, P, cnt, Zt, Ss, ns_, out);
  k_mega<<<1552, 256, 0, stream>>>(qnb, qnbF, pnb, labels, pl, Zt, Ss, ns_, Zpart, part, cntp);
  k_reduce2<<<48, 256, 0, stream>>>(part, cntp, Zpart, P, cnt, Zt);
  k_final<<<128, 256, 0, stream>>>(qn, labels, P, cnt, Zt, Ss, ns_, out);
}

// Round 6
// 81.082 us; speedup vs baseline: 1.6088x; 1.1702x over previous
//
#include <hip/hip_runtime.h>
#include <stdint.h>
#include <math.h>

#define B_N 512
#define M_N 65536
#define D_N 256
#define C_N 10
#define TEMP_INV 14.285714285714286f   // 1/0.07
#define LOG2E_F 1.4426950408889634f
#define K2C (LOG2E_F * TEMP_INV)       // exp(x/T) = exp2(x*K2C)

typedef __attribute__((ext_vector_type(8))) __bf16 bf16x8;
typedef __attribute__((ext_vector_type(4))) float f32x4;

__device__ __forceinline__ unsigned short f2bf(float f) {
  unsigned int u = __float_as_uint(f);
  return (unsigned short)((u + 0x7FFFu + ((u >> 16) & 1u)) >> 16);  // RNE
}
__device__ __forceinline__ float bf2f(unsigned short s) {
  return __uint_as_float(((unsigned int)s) << 16);
}

// K1: fused normalize. Blocks [0,2048): pro_memory -> bf16 pnb (row-major).
// Blocks [2048,2080): q -> f32 qn + bf16 qnb + qnbF (k-chunk-major [32][512][8]).
// Block 0 inits accumulators.
__global__ __launch_bounds__(256) void k_norm_full(const float* __restrict__ pm,
                                                   const float* __restrict__ q,
                                                   unsigned short* __restrict__ pnb,
                                                   float* __restrict__ qn,
                                                   unsigned short* __restrict__ qnb,
                                                   unsigned short* __restrict__ qnbF,
                                                   float* __restrict__ P,
                                                   int* __restrict__ cnt,
                                                   float* __restrict__ Zt,
                                                   float* __restrict__ Ss,
                                                   float* __restrict__ ns_,
                                                   float* __restrict__ out) {
  const int tid = threadIdx.x, w = tid >> 6, l = tid & 63;
  const int g = l >> 4, qs = l & 15;
  if (blockIdx.x == 0) {
    for (int i = tid; i < C_N * D_N; i += 256) P[i] = 0.f;
    if (tid < C_N) cnt[tid] = 0;
    for (int i = tid; i < B_N; i += 256) { Zt[i] = 0.f; Ss[i] = 0.f; ns_[i] = 0.f; }
    if (tid == 0) out[0] = 0.f;
  }
  if (blockIdx.x < 2048) {
    const int rbase = blockIdx.x * 32 + w * 8;
#pragma unroll
    for (int it = 0; it < 2; ++it) {
      const int r = rbase + it * 4 + g;
      const float* src = pm + (size_t)r * D_N;
      float4 v[4];
#pragma unroll
      for (int c = 0; c < 4; ++c) v[c] = *(const float4*)(src + qs * 4 + c * 64);
      float ss = 0.f;
#pragma unroll
      for (int c = 0; c < 4; ++c)
        ss += v[c].x * v[c].x + v[c].y * v[c].y + v[c].z * v[c].z + v[c].w * v[c].w;
      ss += __shfl_xor(ss, 1, 64);
      ss += __shfl_xor(ss, 2, 64);
      ss += __shfl_xor(ss, 4, 64);
      ss += __shfl_xor(ss, 8, 64);
      const float rv = 1.0f / fmaxf(sqrtf(ss), 1e-8f);
      unsigned short* dst = pnb + (size_t)r * D_N;
#pragma unroll
      for (int c = 0; c < 4; ++c) {
        ushort4 o;
        o.x = f2bf(v[c].x * rv); o.y = f2bf(v[c].y * rv);
        o.z = f2bf(v[c].z * rv); o.w = f2bf(v[c].w * rv);
        *(ushort4*)(dst + qs * 4 + c * 64) = o;
      }
    }
  } else {
    const int r = (blockIdx.x - 2048) * 16 + w * 4 + g;
    const float* src = q + (size_t)r * D_N;
    float4 v[4];
#pragma unroll
    for (int c = 0; c < 4; ++c) v[c] = *(const float4*)(src + qs * 4 + c * 64);
    float ss = 0.f;
#pragma unroll
    for (int c = 0; c < 4; ++c)
      ss += v[c].x * v[c].x + v[c].y * v[c].y + v[c].z * v[c].z + v[c].w * v[c].w;
    ss += __shfl_xor(ss, 1, 64);
    ss += __shfl_xor(ss, 2, 64);
    ss += __shfl_xor(ss, 4, 64);
    ss += __shfl_xor(ss, 8, 64);
    const float rv = 1.0f / fmaxf(sqrtf(ss), 1e-8f);
    float* dstf = qn + (size_t)r * D_N;
    unsigned short* dstb = qnb + (size_t)r * D_N;
#pragma unroll
    for (int c = 0; c < 4; ++c) {
      float4 o4;
      o4.x = v[c].x * rv; o4.y = v[c].y * rv; o4.z = v[c].z * rv; o4.w = v[c].w * rv;
      *(float4*)(dstf + qs * 4 + c * 64) = o4;
      ushort4 o;
      o.x = f2bf(o4.x); o.y = f2bf(o4.y); o.z = f2bf(o4.z); o.w = f2bf(o4.w);
      *(ushort4*)(dstb + qs * 4 + c * 64) = o;
      const int kc = (qs >> 1) + c * 8;
      *(ushort4*)(qnbF + (((size_t)kc * 512 + r) << 3) + (qs & 1) * 4) = o;
    }
  }
}

// K2 mega-kernel:
//   blocks [0,1024): Z_mem GEMM over 64 m-rows x all 512 q. B reg-staged into
//     LDS at 544B pitch (bank-slot = (2r+s)&31 -> conflict-free fragment reads),
//     ONE barrier. A-fragments direct from L2-hot qnbF. acc[4][4], 2 bt iters.
//     Z partials -> plain stores to Zpart[bid][512].
//   blocks [1024,1040): src branch (verified 128x128 core).
//   blocks [1040,1552): class partial sums, 1 wave = 1 row (ushort4/lane),
//     register switch-accumulators, LDS cross-wave merge, plain stores.
__global__ __launch_bounds__(256, 4) void k_mega(const unsigned short* __restrict__ qnb,
                                                 const unsigned short* __restrict__ qnbF,
                                                 const unsigned short* __restrict__ pnb,
                                                 const int* __restrict__ labels,
                                                 const int* __restrict__ pl,
                                                 float* __restrict__ Zt,
                                                 float* __restrict__ Ss,
                                                 float* __restrict__ ns_,
                                                 float* __restrict__ Zpart,
                                                 float* __restrict__ part) {
  __shared__ __align__(16) unsigned char smem[40960];
  const int bid = blockIdx.x;
  const int tid = threadIdx.x, w = tid >> 6, lane = tid & 63;
  const int rsel = lane & 15, hi = lane >> 4;

  if (bid < 1024) {
    // ---------------- Z_mem branch ----------------
    unsigned short* Bs = (unsigned short*)smem;            // 64 rows x 544B pitch
    float* zall = (float*)(smem + 34816);                  // [512]
    const unsigned short* Bb = pnb + (size_t)bid * 64 * D_N;
    {
      bf16x8 t8[8];
#pragma unroll
      for (int i = 0; i < 8; ++i) {
        const int c = i * 256 + tid;
        t8[i] = *(const bf16x8*)(Bb + (size_t)c * 8);       // linear, coalesced
      }
#pragma unroll
      for (int i = 0; i < 8; ++i) {
        const int c = i * 256 + tid;
        const int r = c >> 5, s = c & 31;
        *(bf16x8*)((char*)Bs + r * 544 + s * 16) = t8[i];   // padded pitch
      }
    }
    __syncthreads();   // the ONLY barrier before the flush

#pragma unroll
    for (int bt = 0; bt < 2; ++bt) {
      f32x4 acc[4][4];
#pragma unroll
      for (int mi = 0; mi < 4; ++mi)
#pragma unroll
        for (int ni = 0; ni < 4; ++ni)
          acc[mi][ni] = (f32x4){0.f, 0.f, 0.f, 0.f};
#pragma unroll
      for (int it = 0; it < 8; ++it) {
        const int kc = it * 4 + hi;                        // k-chunk per quarter
        bf16x8 af[4], bfr[4];
#pragma unroll
        for (int mi = 0; mi < 4; ++mi) {
          const int r = bt * 256 + w * 64 + mi * 16 + rsel;
          af[mi] = *(const bf16x8*)(qnbF + (((size_t)kc * 512 + r) << 3));
        }
#pragma unroll
        for (int ni = 0; ni < 4; ++ni) {
          const int rB = ni * 16 + rsel;
          bfr[ni] = *(const bf16x8*)((const char*)Bs + rB * 544 + kc * 16);
        }
#pragma unroll
        for (int mi = 0; mi < 4; ++mi)
#pragma unroll
          for (int ni = 0; ni < 4; ++ni)
            acc[mi][ni] = __builtin_amdgcn_mfma_f32_16x16x32_bf16(af[mi], bfr[ni], acc[mi][ni], 0, 0, 0);
      }
      // epilogue for this q-half: sum exp over this block's 64 m-cols
#pragma unroll
      for (int mi = 0; mi < 4; ++mi) {
        float sv[4] = {0.f, 0.f, 0.f, 0.f};
#pragma unroll
        for (int ni = 0; ni < 4; ++ni)
#pragma unroll
          for (int rg = 0; rg < 4; ++rg)
            sv[rg] += __builtin_amdgcn_exp2f(acc[mi][ni][rg] * K2C);
#pragma unroll
        for (int rg = 0; rg < 4; ++rg) {
          float v = sv[rg];
          v += __shfl_xor(v, 1, 64);
          v += __shfl_xor(v, 2, 64);
          v += __shfl_xor(v, 4, 64);
          v += __shfl_xor(v, 8, 64);
          if (rsel == 0)
            zall[bt * 256 + w * 64 + mi * 16 + hi * 4 + rg] = v;  // owner-unique
        }
      }
    }
    __syncthreads();
    float* zp = Zpart + (size_t)bid * 512;
    for (int i = tid; i < 512; i += 256) zp[i] = zall[i];
  } else if (bid < 1040) {
    // ---------------- src branch (verified 128x128 core) ----------------
    unsigned short* As = (unsigned short*)smem;            // 128x64
    unsigned short* Bs = (unsigned short*)(smem + 16384);  // 128x64
    int* labR = (int*)(smem + 32768);
    int* labJ = (int*)(smem + 33280);
    float* zr = (float*)(smem + 33792);
    float* sr = (float*)(smem + 34304);
    float* nr = (float*)(smem + 34816);
    const int sb_id = bid - 1024;
    const int bt = sb_id >> 2, jt = sb_id & 3;
    const unsigned short* Ab = qnb + (size_t)(bt * 128) * D_N;
    const unsigned short* Bb = qnb + (size_t)(jt * 128) * D_N;
    if (tid < 128) {
      labR[tid] = labels[bt * 128 + tid];
      labJ[tid] = labels[jt * 128 + tid];
      zr[tid] = 0.f; sr[tid] = 0.f; nr[tid] = 0.f;
    }
    f32x4 acc[4][4];
#pragma unroll
    for (int mi = 0; mi < 4; ++mi)
#pragma unroll
      for (int ni = 0; ni < 4; ++ni)
        acc[mi][ni] = (f32x4){0.f, 0.f, 0.f, 0.f};
    const int wr = w >> 1, wc = w & 1;
    for (int ks = 0; ks < 4; ++ks) {
      const int kk = ks * 64;
#pragma unroll
      for (int i = 0; i < 4; ++i) {
        const int cbase = i * 256 + w * 64;
        const int c = cbase + lane;
        const int r = c >> 3;
        const int ss2 = (c & 7) ^ (r & 7);
        __builtin_amdgcn_global_load_lds(
            (const __attribute__((address_space(1))) void*)(Ab + (size_t)r * D_N + kk + ss2 * 8),
            (__attribute__((address_space(3))) void*)(As + cbase * 8), 16, 0, 0);
        __builtin_amdgcn_global_load_lds(
            (const __attribute__((address_space(1))) void*)(Bb + (size_t)r * D_N + kk + ss2 * 8),
            (__attribute__((address_space(3))) void*)(Bs + cbase * 8), 16, 0, 0);
      }
      __syncthreads();
#pragma unroll
      for (int ksl = 0; ksl < 2; ++ksl) {
        const int sb = ksl * 4 + hi;
        bf16x8 af[4], bfr[4];
#pragma unroll
        for (int mi = 0; mi < 4; ++mi) {
          const int r = wr * 64 + mi * 16 + rsel;
          af[mi] = *(const bf16x8*)((const char*)As + r * 128 + ((sb ^ (r & 7)) * 16));
        }
#pragma unroll
        for (int ni = 0; ni < 4; ++ni) {
          const int r = wc * 64 + ni * 16 + rsel;
          bfr[ni] = *(const bf16x8*)((const char*)Bs + r * 128 + ((sb ^ (r & 7)) * 16));
        }
#pragma unroll
        for (int mi = 0; mi < 4; ++mi)
#pragma unroll
          for (int ni = 0; ni < 4; ++ni)
            acc[mi][ni] = __builtin_amdgcn_mfma_f32_16x16x32_bf16(af[mi], bfr[ni], acc[mi][ni], 0, 0, 0);
      }
      __syncthreads();
    }
#pragma unroll
    for (int mi = 0; mi < 4; ++mi) {
      float zs[4] = {0.f, 0.f, 0.f, 0.f};
      float sv[4] = {0.f, 0.f, 0.f, 0.f};
      float nv[4] = {0.f, 0.f, 0.f, 0.f};
#pragma unroll
      for (int ni = 0; ni < 4; ++ni) {
        const int j_loc = wc * 64 + ni * 16 + rsel;
        const int jg = jt * 128 + j_loc;
        const int lj = labJ[j_loc];
#pragma unroll
        for (int rg_ = 0; rg_ < 4; ++rg_) {
          const int r_loc = wr * 64 + mi * 16 + hi * 4 + rg_;
          const int rg = bt * 128 + r_loc;
          const float lg = acc[mi][ni][rg_] * TEMP_INV - TEMP_INV;
          if (rg != jg) {
            zs[rg_] += __builtin_amdgcn_exp2f(lg * LOG2E_F);
            if (labR[r_loc] == lj) { sv[rg_] += lg; nv[rg_] += 1.f; }
          }
        }
      }
#pragma unroll
      for (int rg_ = 0; rg_ < 4; ++rg_) {
        float z = zs[rg_], s = sv[rg_], n = nv[rg_];
        z += __shfl_xor(z, 1, 64); z += __shfl_xor(z, 2, 64);
        z += __shfl_xor(z, 4, 64); z += __shfl_xor(z, 8, 64);
        s += __shfl_xor(s, 1, 64); s += __shfl_xor(s, 2, 64);
        s += __shfl_xor(s, 4, 64); s += __shfl_xor(s, 8, 64);
        n += __shfl_xor(n, 1, 64); n += __shfl_xor(n, 2, 64);
        n += __shfl_xor(n, 4, 64); n += __shfl_xor(n, 8, 64);
        if (rsel == 0) {
          const int r_loc = wr * 64 + mi * 16 + hi * 4 + rg_;
          atomicAdd(&zr[r_loc], z);
          atomicAdd(&sr[r_loc], s);
          atomicAdd(&nr[r_loc], n);
        }
      }
    }
    __syncthreads();
    if (tid < 128) {
      atomicAdd(&Zt[bt * 128 + tid], zr[tid]);
      atomicAdd(&Ss[bt * 128 + tid], sr[tid]);
      atomicAdd(&ns_[bt * 128 + tid], nr[tid]);
    }
  } else {
    // ---------------- class partial-sum branch ----------------
    const int cb = bid - 1040;           // 0..511
    const int rbase = cb * 128;
    float4 a0 = {0,0,0,0}, a1 = {0,0,0,0}, a2 = {0,0,0,0}, a3 = {0,0,0,0}, a4 = {0,0,0,0};
    float4 a5 = {0,0,0,0}, a6 = {0,0,0,0}, a7 = {0,0,0,0}, a8 = {0,0,0,0}, a9 = {0,0,0,0};
    for (int j = 0; j < 32; ++j) {
      const int row = rbase + j * 4 + w;                   // one row per wave
      const ushort4 u = *(const ushort4*)(pnb + (size_t)row * D_N + lane * 4);
      float4 v;
      v.x = bf2f(u.x); v.y = bf2f(u.y); v.z = bf2f(u.z); v.w = bf2f(u.w);
      const int cls = pl[row];                             // wave-uniform
      switch (cls) {
        case 0: a0.x += v.x; a0.y += v.y; a0.z += v.z; a0.w += v.w; break;
        case 1: a1.x += v.x; a1.y += v.y; a1.z += v.z; a1.w += v.w; break;
        case 2: a2.x += v.x; a2.y += v.y; a2.z += v.z; a2.w += v.w; break;
        case 3: a3.x += v.x; a3.y += v.y; a3.z += v.z; a3.w += v.w; break;
        case 4: a4.x += v.x; a4.y += v.y; a4.z += v.z; a4.w += v.w; break;
        case 5: a5.x += v.x; a5.y += v.y; a5.z += v.z; a5.w += v.w; break;
        case 6: a6.x += v.x; a6.y += v.y; a6.z += v.z; a6.w += v.w; break;
        case 7: a7.x += v.x; a7.y += v.y; a7.z += v.z; a7.w += v.w; break;
        case 8: a8.x += v.x; a8.y += v.y; a8.z += v.z; a8.w += v.w; break;
        default: a9.x += v.x; a9.y += v.y; a9.z += v.z; a9.w += v.w; break;
      }
    }
    float* Pl = (float*)smem;                              // [4][10][256] = 40960 B
#define WRCLS(k, ak) *(float4*)(Pl + ((w * 10 + (k)) * 256 + lane * 4)) = ak;
    WRCLS(0, a0) WRCLS(1, a1) WRCLS(2, a2) WRCLS(3, a3) WRCLS(4, a4)
    WRCLS(5, a5) WRCLS(6, a6) WRCLS(7, a7) WRCLS(8, a8) WRCLS(9, a9)
#undef WRCLS
    __syncthreads();
    float* dst = part + (size_t)cb * (C_N * D_N);
    for (int i = tid; i < C_N * D_N; i += 256)
      dst[i] = Pl[i] + Pl[2560 + i] + Pl[5120 + i] + Pl[7680 + i];
  }
}

// K3: fused reductions. Blocks [0,40): class partials -> P, counts from pl.
// Blocks [40,48): Zpart columns -> Zt (+=, after src atomics are in).
__global__ __launch_bounds__(256) void k_reduce2(const float* __restrict__ part,
                                                 const int* __restrict__ pl,
                                                 const float* __restrict__ Zpart,
                                                 float* __restrict__ P,
                                                 int* __restrict__ cnt,
                                                 float* __restrict__ Zt) {
  const int tid = threadIdx.x, w = tid >> 6, lane = tid & 63;
  if (blockIdx.x < 40) {
    __shared__ int xs[4];
    const int c = blockIdx.x >> 2, q = blockIdx.x & 3;
    float s = 0.f;
#pragma unroll 8
    for (int i = 0; i < 128; ++i)
      s += part[(size_t)(q * 128 + i) * (C_N * D_N) + c * 256 + tid];
    atomicAdd(&P[c * 256 + tid], s);
    int x = 0;
    const int* plq = pl + q * 16384;
#pragma unroll 8
    for (int jj = 0; jj < 64; ++jj)
      x += (plq[jj * 256 + tid] == c) ? 1 : 0;
    x += __shfl_xor(x, 32, 64);
    x += __shfl_xor(x, 16, 64);
    x += __shfl_xor(x, 8, 64);
    x += __shfl_xor(x, 4, 64);
    x += __shfl_xor(x, 2, 64);
    x += __shfl_xor(x, 1, 64);
    if (lane == 0) xs[w] = x;
    __syncthreads();
    if (tid == 0) atomicAdd(&cnt[c], xs[0] + xs[1] + xs[2] + xs[3]);
  } else {
    __shared__ float zl[4][64];
    const int zb = blockIdx.x - 40;
    const int b = zb * 64 + (tid & 63);
    const int s = tid >> 6;
    float acc = 0.f;
#pragma unroll 8
    for (int k = 0; k < 256; ++k)
      acc += Zpart[(size_t)(s * 256 + k) * 512 + b];
    zl[s][tid & 63] = acc;
    __syncthreads();
    if (tid < 64)
      Zt[zb * 64 + tid] += zl[0][tid] + zl[1][tid] + zl[2][tid] + zl[3][tid];
  }
}

// K4: loss. 128 blocks, 1 row per wave.
__global__ __launch_bounds__(256) void k_final(const float* __restrict__ qn,
                                               const int* __restrict__ labels,
                                               const float* __restrict__ P,
                                               const int* __restrict__ cnt,
                                               const float* __restrict__ Zt,
                                               const float* __restrict__ Ss,
                                               const float* __restrict__ ns_,
                                               float* __restrict__ out) {
  __shared__ float partl[4];
  const int tid = threadIdx.x, w = tid >> 6, lane = tid & 63;
  const int b = blockIdx.x * 4 + w;
  const int cls = labels[b];
  const float4 v = *(const float4*)(qn + (size_t)b * D_N + lane * 4);
  const float4 p = *(const float4*)(P + (size_t)cls * D_N + lane * 4);
  float d = v.x * p.x + v.y * p.y + v.z * p.z + v.w * p.w;
  d += __shfl_xor(d, 32, 64);
  d += __shfl_xor(d, 16, 64);
  d += __shfl_xor(d, 8, 64);
  d += __shfl_xor(d, 4, 64);
  d += __shfl_xor(d, 2, 64);
  d += __shfl_xor(d, 1, 64);
  if (lane == 0) {
    const float smem_ = d * TEMP_INV;
    const float ntot = ns_[b] + (float)cnt[cls];
    partl[w] = (Ss[b] + smem_) / ntot - logf(Zt[b]);
  }
  __syncthreads();
  if (tid == 0)
    atomicAdd(out, -(partl[0] + partl[1] + partl[2] + partl[3]) * (1.0f / (float)B_N));
}

extern "C" void kernel_launch(void* const* d_in, const int* in_sizes, int n_in,
                              void* d_out, int out_size, void* d_ws, size_t ws_size,
                              hipStream_t stream) {
  const float* q = (const float*)d_in[0];
  const int* labels = (const int*)d_in[1];
  const float* pm = (const float*)d_in[2];
  const int* pl = (const int*)d_in[3];
  float* out = (float*)d_out;

  char* wsb = (char*)d_ws;
  unsigned short* pnb = (unsigned short*)wsb;              // 33,554,432 B
  float* qn = (float*)(wsb + 33554432);                    // 524,288 B
  unsigned short* qnb = (unsigned short*)(wsb + 34078720); // 262,144 B
  float* P = (float*)(wsb + 34340864);                     // 10,240 B
  int* cnt = (int*)(wsb + 34351104);                       // 64 B
  float* Zt = (float*)(wsb + 34351168);                    // 2,048 B
  float* Ss = (float*)(wsb + 34353216);                    // 2,048 B
  float* ns_ = (float*)(wsb + 34355264);                   // 2,048 B
  float* part = (float*)(wsb + 34357312);                  // 512*2560*4 = 5,242,880 B
  float* Zpart = (float*)(wsb + 39620672);                 // 1024*512*4 = 2,097,152 B
  unsigned short* qnbF = (unsigned short*)(wsb + 41717824);// 32*512*8*2 = 262,144 B

  k_norm_full<<<2080, 256, 0, stream>>>(pm, q, pnb, qn, qnb, qnbF, P, cnt, Zt, Ss, ns_, out);
  k_mega<<<1552, 256, 0, stream>>>(qnb, qnbF, pnb, labels, pl, Zt, Ss, ns_, Zpart, part);
  k_reduce2<<<48, 256, 0, stream>>>(part, pl, Zpart, P, cnt, Zt);
  k_final<<<128, 256, 0, stream>>>(qn, labels, P, cnt, Zt, Ss, ns_, out);
}